// Round 7
// baseline (3316.892 us; speedup 1.0000x reference)
//
#include <hip/hip_runtime.h>
#include <hip/hip_bf16.h>

#define B_   32
#define T_   2048
#define DIN  512
#define DM   1024
#define K_   64
#define BT   64
#define NC   (T_/BT)    // 32 chunks
#define MT   (DM/64)    // 16 m-tiles
#define LDSTR 68        // SIMT fallback LDS stride
#define G_   2          // chunks per k-pass group (MFMA kernel)
#define WROW 40         // LDS W row stride in bf16 (32 + 8 pad; 80B, 16B-aligned)

typedef unsigned short u16;
typedef unsigned int   u32;
typedef __attribute__((ext_vector_type(8))) short bf16x8;   // 8 bf16 = 4 VGPRs
typedef __attribute__((ext_vector_type(4))) float f32x4;

__device__ __forceinline__ float bf2f(u16 h) {
    return __uint_as_float(((u32)h) << 16);
}
__device__ __forceinline__ void bf2x2(u32 w, float& lo, float& hi) {
    lo = __uint_as_float(w << 16);
    hi = __uint_as_float(w & 0xffff0000u);
}
__device__ __forceinline__ u16 f2bf(float f) {   // round-to-nearest-even
    u32 u = __float_as_uint(f);
    u += 0x7fffu + ((u >> 16) & 1u);
    return (u16)(u >> 16);
}
__device__ __forceinline__ float softplusf(float z) {
    return fmaxf(z, 0.0f) + log1pf(expf(-fabsf(z)));
}

// ---- dtype-agnostic loaders (v3 verbatim) ---------------------------------
template<bool BF16>
__device__ __forceinline__ float ld1(const void* p, size_t i) {
    if (BF16) return bf2f(((const u16*)p)[i]);
    else      return ((const float*)p)[i];
}
template<bool BF16>
__device__ __forceinline__ void ld2(const void* p, size_t i, float& a, float& b) {
    if (BF16) { u32 w = *(const u32*)((const u16*)p + i); bf2x2(w, a, b); }
    else      { float2 v = *(const float2*)((const float*)p + i); a = v.x; b = v.y; }
}
template<bool BF16>
__device__ __forceinline__ void ld8(const void* p, size_t i, float* a) {
    if (BF16) {
        uint4 v = *(const uint4*)((const u16*)p + i);
        bf2x2(v.x, a[0], a[1]); bf2x2(v.y, a[2], a[3]);
        bf2x2(v.z, a[4], a[5]); bf2x2(v.w, a[6], a[7]);
    } else {
        float4 v0 = *(const float4*)((const float*)p + i);
        float4 v1 = *(const float4*)((const float*)p + i + 4);
        a[0]=v0.x; a[1]=v0.y; a[2]=v0.z; a[3]=v0.w;
        a[4]=v1.x; a[5]=v1.y; a[6]=v1.z; a[7]=v1.w;
    }
}

// ---- device-side dtype sniff (v3 verbatim) --------------------------------
__device__ __forceinline__ bool sniff_is_bf16(const void* xraw) {
    __shared__ int flag_s;
    if (threadIdx.x < 64) {
        u16 w = ((const u16*)xraw)[threadIdx.x];
        float av = fabsf(bf2f(w));
        bool plausible = (av == 0.0f) || (av >= 9.094947e-13f && av <= 64.0f);
        unsigned long long m = __ballot(plausible ? 1 : 0);
        if (threadIdx.x == 0) flag_s = (__popcll(m) >= 56) ? 1 : 0;
    }
    __syncthreads();
    return flag_s != 0;
}

// ---------------------------------------------------------------------------
// zero-init fp32 accumulator region inside d_out (v3 verbatim).
// ---------------------------------------------------------------------------
__global__ __launch_bounds__(64) void zero_accum_kernel(const void* x, void* out) {
    bool isbf = sniff_is_bf16(x);
    float* outf = (float*)out;
    if (threadIdx.x < 32) {
        if (isbf) outf[threadIdx.x] = 0.0f;
        else      outf[64 + threadIdx.x] = 0.0f;
    }
}

// ---------------------------------------------------------------------------
// NEW: bf16 fused SSM via MFMA. Same grid/launch as v3's fused (512 x 256),
// same sniff gate, same atomicAdd ending. Only the GEMM internals changed.
// ---------------------------------------------------------------------------
__global__ __launch_bounds__(256) void fused_mfma_bf16(
    const void* __restrict__ xv,
    const void* __restrict__ Wlamv, const void* __restrict__ blamv,
    const void* __restrict__ Wdeltv, const void* __restrict__ bdeltv,
    const void* __restrict__ Winpv, const void* __restrict__ binpv,
    const void* __restrict__ Waddv,
    void* __restrict__ out)
{
    if (!sniff_is_bf16(xv)) return;
    const u16* x     = (const u16*)xv;
    const u16* Wlam  = (const u16*)Wlamv;
    const u16* Wdelt = (const u16*)Wdeltv;
    const u16* Winp  = (const u16*)Winpv;
    const u16* blam  = (const u16*)blamv;
    const u16* bdelt = (const u16*)bdeltv;
    const u16* binp  = (const u16*)binpv;
    const u16* Wadd  = (const u16*)Waddv;

    __shared__ __align__(16) u16 WT_s[3 * 64 * WROW];   // 15360 B
    __shared__ float segA[64 * 17];                     // 4352 B
    __shared__ float segD[64 * 17];                     // 4352 B

    const int mt   = blockIdx.x & 15;
    const int b    = blockIdx.x >> 4;
    const int tid  = threadIdx.x;
    const int R    = tid >> 6;        // wave id = row tile (0..3)
    const int lane = tid & 63;
    const int l15  = lane & 15;
    const int q    = lane >> 4;       // quad id

    // staging decomposition (tid<192): mat = tid>>6, kappa pair, m 16-group
    const int sg4  = tid & 3;
    const int sp   = (tid >> 2) & 15;
    const int smat = tid >> 6;
    const u16* sW  = (smat == 0) ? Wlam : (smat == 1) ? Wdelt : Winp;

    float bl[4], bd[4], bi[4];
    #pragma unroll
    for (int C = 0; C < 4; C++) {
        int m = mt*64 + C*16 + l15;
        bl[C] = bf2f(blam[m]); bd[C] = bf2f(bdelt[m]); bi[C] = bf2f(binp[m]);
    }

    float scarry = 0.0f;   // scan state (wave 0: column m = mt*64 + tid)

    for (int grp = 0; grp < NC / G_; grp++) {
        f32x4 acc0[3][4], acc1[3][4];      // [mat][C] for chunk 0/1 of group
        #pragma unroll
        for (int C = 0; C < 4; C++) {
            acc0[0][C] = (f32x4){bl[C], bl[C], bl[C], bl[C]};
            acc0[1][C] = (f32x4){bd[C], bd[C], bd[C], bd[C]};
            acc0[2][C] = (f32x4){bi[C], bi[C], bi[C], bi[C]};
            acc1[0][C] = acc0[0][C]; acc1[1][C] = acc0[1][C]; acc1[2][C] = acc0[2][C];
        }

        const u16* aRow0 = x + ((size_t)(b*T_ + (grp*G_ + 0)*BT + R*16 + l15))*DIN + q*8;
        const u16* aRow1 = x + ((size_t)(b*T_ + (grp*G_ + 1)*BT + R*16 + l15))*DIN + q*8;

        for (int kk = 0; kk < DIN/32; kk++) {     // 16 k-steps of 32
            const int kk0 = kk * 32;
            if (tid < 192) {   // stage W[kk0..+32][mt tile] transposed into LDS
                const u16* src = sW + (size_t)(kk0 + 2*sp)*DM + mt*64 + sg4*16;
                uint4 va0 = *(const uint4*)(src);
                uint4 va1 = *(const uint4*)(src + 8);
                uint4 vb0 = *(const uint4*)(src + DM);
                uint4 vb1 = *(const uint4*)(src + DM + 8);
                const int mbase = smat*64 + sg4*16;
                u32 a[4] = {va0.x, va0.y, va0.z, va0.w};
                u32 bq[4] = {vb0.x, vb0.y, vb0.z, vb0.w};
                #pragma unroll
                for (int j = 0; j < 4; j++) {
                    u32 e = (a[j] & 0xFFFFu) | (bq[j] << 16);           // m even
                    u32 o = (a[j] >> 16) | (bq[j] & 0xFFFF0000u);       // m odd
                    *(u32*)&WT_s[(mbase + 2*j    )*WROW + 2*sp] = e;
                    *(u32*)&WT_s[(mbase + 2*j + 1)*WROW + 2*sp] = o;
                }
                u32 a2[4] = {va1.x, va1.y, va1.z, va1.w};
                u32 b2[4] = {vb1.x, vb1.y, vb1.z, vb1.w};
                #pragma unroll
                for (int j = 0; j < 4; j++) {
                    u32 e = (a2[j] & 0xFFFFu) | (b2[j] << 16);
                    u32 o = (a2[j] >> 16) | (b2[j] & 0xFFFF0000u);
                    *(u32*)&WT_s[(mbase + 8 + 2*j    )*WROW + 2*sp] = e;
                    *(u32*)&WT_s[(mbase + 8 + 2*j + 1)*WROW + 2*sp] = o;
                }
            }
            __syncthreads();

            bf16x8 Af0 = *(const bf16x8*)(aRow0 + kk0);
            bf16x8 Af1 = *(const bf16x8*)(aRow1 + kk0);
            #pragma unroll
            for (int mat = 0; mat < 3; mat++)
                #pragma unroll
                for (int C = 0; C < 4; C++) {
                    bf16x8 Bf = *(const bf16x8*)&WT_s[(mat*64 + C*16 + l15)*WROW + q*8];
                    acc0[mat][C] = __builtin_amdgcn_mfma_f32_16x16x32_bf16(
                        Af0, Bf, acc0[mat][C], 0, 0, 0);
                    acc1[mat][C] = __builtin_amdgcn_mfma_f32_16x16x32_bf16(
                        Af1, Bf, acc1[mat][C], 0, 0, 0);
                }
            __syncthreads();   // before next stage overwrites WT_s
        }

        // per-chunk epilogue: activations, seg-compose, scan fold
        #pragma unroll
        for (int cc = 0; cc < G_; cc++) {
            #pragma unroll
            for (int C = 0; C < 4; C++) {
                float Aseg = 1.0f, Dseg = 0.0f;
                #pragma unroll
                for (int r = 0; r < 4; r++) {
                    float v0 = (cc == 0) ? acc0[0][C][r] : acc1[0][C][r];
                    float v1 = (cc == 0) ? acc0[1][C][r] : acc1[1][C][r];
                    float v2 = (cc == 0) ? acc0[2][C][r] : acc1[2][C][r];
                    float lam = softplusf(v0);
                    float dl  = softplusf(v1);
                    float aa  = expf(-dl * lam);
                    float dd  = dl * v2;
                    Dseg = fmaf(aa, Dseg, dd);   // t ascending within 4-row run
                    Aseg *= aa;
                }
                // C/D layout: col = C*16+l15, t-row = R*16 + q*4 + r
                segA[(C*16 + l15)*17 + R*4 + q] = Aseg;
                segD[(C*16 + l15)*17 + R*4 + q] = Dseg;
            }
            __syncthreads();
            if (tid < 64) {     // fold 16 segs (t-order) for column tid
                float s = scarry;
                #pragma unroll
                for (int seg = 0; seg < 16; seg++)
                    s = fmaf(segA[tid*17 + seg], s, segD[tid*17 + seg]);
                scarry = s;
            }
            __syncthreads();
        }
    }

    if (tid < 64) {
        float partial = scarry * bf2f(Wadd[mt*64 + tid]);
        #pragma unroll
        for (int off = 32; off > 0; off >>= 1)
            partial += __shfl_down(partial, off, 64);
        if (tid == 0) atomicAdd(&((float*)out)[b], partial);
    }
}

// ---------------------------------------------------------------------------
// v3 SIMT fused kernel (templated) — only <false> (fp32) instantiation used.
// ---------------------------------------------------------------------------
template<bool BF16>
__global__ __launch_bounds__(256) void fused_ssm_kernel(
    const void* __restrict__ x,
    const void* __restrict__ Wlam, const void* __restrict__ blam,
    const void* __restrict__ Wdelt, const void* __restrict__ bdelt,
    const void* __restrict__ Winp, const void* __restrict__ binp,
    const void* __restrict__ Wadd,
    void* __restrict__ out)
{
    if (sniff_is_bf16(x) != BF16) return;

    __shared__ __align__(16) float smem[8704];

    const int mt  = blockIdx.x & 15;
    const int b   = blockIdx.x >> 4;
    const int tid = threadIdx.x;
    const int tx  = tid & 15;
    const int ty  = tid >> 4;

    float bl[4], bd[4], bi[4];
    #pragma unroll
    for (int jj = 0; jj < 4; jj++) {
        int m = mt*64 + tx*4 + jj;
        bl[jj] = ld1<BF16>(blam, m); bd[jj] = ld1<BF16>(bdelt, m); bi[jj] = ld1<BF16>(binp, m);
    }

    float* xsT = smem;
    float* w3  = smem + 32*LDSTR;
    float* alphaS = smem;
    float* driveS = smem + 64*LDSTR;

    const int t_s = tid >> 2;
    const int ko  = (tid & 3) * 8;
    const int wk  = tid >> 3;
    const int wmo = (tid & 7) * 8;

    float scarry = 0.0f;

    for (int c = 0; c < NC; c++) {
        float acc0[4][4], acc1[4][4], acc2[4][4];
        #pragma unroll
        for (int ii = 0; ii < 4; ii++)
            #pragma unroll
            for (int jj = 0; jj < 4; jj++) {
                acc0[ii][jj] = bl[jj]; acc1[ii][jj] = bd[jj]; acc2[ii][jj] = bi[jj];
            }

        const size_t xbase = ((size_t)b*T_ + (size_t)c*BT) * DIN;

        for (int kk0 = 0; kk0 < DIN; kk0 += 32) {
            {
                float a[8];
                ld8<BF16>(x, xbase + (size_t)t_s*DIN + kk0 + ko, a);
                #pragma unroll
                for (int qq = 0; qq < 8; qq++)
                    xsT[(ko + qq)*LDSTR + t_s] = a[qq];
            }
            #pragma unroll
            for (int mat = 0; mat < 3; mat++) {
                const void* Wp = (mat == 0) ? Wlam : (mat == 1) ? Wdelt : Winp;
                float a[8];
                ld8<BF16>(Wp, (size_t)(kk0 + wk)*DM + mt*64 + wmo, a);
                float* dst = &w3[(mat*32 + wk)*LDSTR + wmo];
                *(float4*)(dst)     = make_float4(a[0],a[1],a[2],a[3]);
                *(float4*)(dst + 4) = make_float4(a[4],a[5],a[6],a[7]);
            }
            __syncthreads();

            #pragma unroll 8
            for (int kkk = 0; kkk < 32; kkk++) {
                float4 xa = *(const float4*)&xsT[kkk*LDSTR + ty*4];
                float4 w0 = *(const float4*)&w3[( 0 + kkk)*LDSTR + tx*4];
                float4 w1 = *(const float4*)&w3[(32 + kkk)*LDSTR + tx*4];
                float4 w2 = *(const float4*)&w3[(64 + kkk)*LDSTR + tx*4];
                float xv[4]  = {xa.x, xa.y, xa.z, xa.w};
                float w0v[4] = {w0.x, w0.y, w0.z, w0.w};
                float w1v[4] = {w1.x, w1.y, w1.z, w1.w};
                float w2v[4] = {w2.x, w2.y, w2.z, w2.w};
                #pragma unroll
                for (int ii = 0; ii < 4; ii++)
                    #pragma unroll
                    for (int jj = 0; jj < 4; jj++) {
                        acc0[ii][jj] = fmaf(xv[ii], w0v[jj], acc0[ii][jj]);
                        acc1[ii][jj] = fmaf(xv[ii], w1v[jj], acc1[ii][jj]);
                        acc2[ii][jj] = fmaf(xv[ii], w2v[jj], acc2[ii][jj]);
                    }
            }
            __syncthreads();
        }

        #pragma unroll
        for (int ii = 0; ii < 4; ii++) {
            int t = ty*4 + ii;
            float a[4], d[4];
            #pragma unroll
            for (int jj = 0; jj < 4; jj++) {
                float lam = softplusf(acc0[ii][jj]);
                float dl  = softplusf(acc1[ii][jj]);
                a[jj] = expf(-dl * lam);
                d[jj] = dl * acc2[ii][jj];
            }
            *(float4*)&alphaS[t*LDSTR + tx*4] = make_float4(a[0],a[1],a[2],a[3]);
            *(float4*)&driveS[t*LDSTR + tx*4] = make_float4(d[0],d[1],d[2],d[3]);
        }
        __syncthreads();

        if (tid < 64) {
            float s = scarry;
            #pragma unroll 8
            for (int t = 0; t < BT; t++)
                s = fmaf(alphaS[t*LDSTR + tid], s, driveS[t*LDSTR + tid]);
            scarry = s;
        }
        __syncthreads();
    }

    if (tid < 64) {
        float partial = scarry * ld1<BF16>(Wadd, mt*64 + tid);
        #pragma unroll
        for (int off = 32; off > 0; off >>= 1)
            partial += __shfl_down(partial, off, 64);
        if (tid == 0) {
            float* outf = (float*)out;
            atomicAdd(BF16 ? &outf[b] : &outf[64 + b], partial);
        }
    }
}

// ---------------------------------------------------------------------------
// add_pred finalize (v3 verbatim).
// ---------------------------------------------------------------------------
template<bool BF16>
__global__ __launch_bounds__(64) void add_finalize_kernel(
    const void* x, const void* badd, void* out)
{
    if (sniff_is_bf16(x) != BF16) return;
    float bb = ld1<BF16>(badd, 0);
    if (threadIdx.x < 32) {
        float* outf = (float*)out;
        if (BF16) {
            float s = outf[threadIdx.x] + bb;
            ((u16*)out)[64 + threadIdx.x] = f2bf(s);
        } else {
            outf[64 + threadIdx.x] += bb;
        }
    }
}

// ---------------------------------------------------------------------------
// Parity (v3 verbatim, 256 threads).
// ---------------------------------------------------------------------------
template<bool BF16>
__global__ __launch_bounds__(256) void parity_kernel(
    const void* __restrict__ x, const void* __restrict__ Wth, const void* __restrict__ bth,
    const void* __restrict__ Wpar, const void* __restrict__ bpar, void* __restrict__ out)
{
    if (sniff_is_bf16(x) != BF16) return;

    __shared__ float xsL[512];
    __shared__ float red[256];
    __shared__ float cosL[64], sinL[64];
    const int b = blockIdx.x;
    const int tid = threadIdx.x;

    {
        float s0 = 0.0f, s1 = 0.0f;
        const size_t xb = (size_t)b * T_ * DIN;
        for (int t = 0; t < T_; t++) {
            float a, c2;
            ld2<BF16>(x, xb + (size_t)t*DIN + 2*tid, a, c2);
            s0 += a; s1 += c2;
        }
        xsL[2*tid] = s0; xsL[2*tid + 1] = s1;
    }
    __syncthreads();

    {
        const int k = tid & 63, seg = tid >> 6;
        float s = 0.0f;
        #pragma unroll 8
        for (int dd = 0; dd < 128; dd++) {
            int d = seg*128 + dd;
            s = fmaf(xsL[d], ld1<BF16>(Wth, (size_t)d*K_ + k), s);
        }
        red[tid] = s;
    }
    __syncthreads();

    if (tid < 64) {
        float s = red[tid] + red[64 + tid] + red[128 + tid] + red[192 + tid];
        float ang = 3.14159265358979323846f * (s + 2048.0f * ld1<BF16>(bth, tid));
        cosL[tid] = cosf(ang);
        sinL[tid] = sinf(ang);
    }
    __syncthreads();

    if (tid < 2) {
        const int j = tid;
        float s = ld1<BF16>(bpar, j);
        for (int k = 0; k < 64; k++) {
            s = fmaf(cosL[k], ld1<BF16>(Wpar, k*2 + j), s);
            s = fmaf(sinL[k], ld1<BF16>(Wpar, (64 + k)*2 + j), s);
        }
        if (BF16) ((u16*)out)[b*2 + j] = f2bf(s);
        else      ((float*)out)[b*2 + j] = s;
    }
}

extern "C" void kernel_launch(void* const* d_in, const int* in_sizes, int n_in,
                              void* d_out, int out_size, void* d_ws, size_t ws_size,
                              hipStream_t stream)
{
    const void* x     = d_in[0];
    const void* Wth   = d_in[1];
    const void* bth   = d_in[2];
    const void* Wlam  = d_in[3];
    const void* blam  = d_in[4];
    const void* Wdelt = d_in[5];
    const void* bdelt = d_in[6];
    const void* Winp  = d_in[7];
    const void* binp  = d_in[8];
    const void* Wpar  = d_in[9];
    const void* bpar  = d_in[10];
    const void* Wadd  = d_in[11];
    const void* badd  = d_in[12];
    (void)d_ws; (void)ws_size;   // workspace deliberately unused (v3-proven path)

    zero_accum_kernel<<<1, 64, 0, stream>>>(x, d_out);

    fused_mfma_bf16<<<B_*MT, 256, 0, stream>>>(
        x, Wlam, blam, Wdelt, bdelt, Winp, binp, Wadd, d_out);
    fused_ssm_kernel<false><<<B_*MT, 256, 0, stream>>>(
        x, Wlam, blam, Wdelt, bdelt, Winp, binp, Wadd, d_out);

    add_finalize_kernel<true ><<<1, 64, 0, stream>>>(x, badd, d_out);
    add_finalize_kernel<false><<<1, 64, 0, stream>>>(x, badd, d_out);

    parity_kernel<true ><<<B_, 256, 0, stream>>>(x, Wth, bth, Wpar, bpar, d_out);
    parity_kernel<false><<<B_, 256, 0, stream>>>(x, Wth, bth, Wpar, bpar, d_out);
}